// Round 10
// baseline (85040.631 us; speedup 1.0000x reference)
//
#include <hip/hip_runtime.h>

// Adaptive binary arithmetic decoder — inherently serial; one wave, lane 0.
// Round-10: 2-symbol speculative super-iteration. The loop-carried chain per
// TWO symbols is ~one symbol's chain + selects:
//  - children (C) + grandchildren (G) entries read ONE ITERATION AHEAD
//    (contiguous, 3x ds_read_b128) so LDS latency overlaps a full iteration
//  - speculative dual model-update (shared v_rcp, select by bit) keeps the
//    pf chain off the recurrence
//  - staleness exactly: self-loop (s1==st), s2 in {st,s1}, and one
//    deferred-read miss (== prev iteration's s1) -> 2 cndmask patches +
//    3 rare cold branches
//  - all arithmetic identical to the HW-verified r8 forms (absmax=0 x3)

#define WORDS_LDS 16400   // 16384 payload words + zero pad (524288 bits)
#define MAX_STATES 1024
#define OBITS_WORDS 8192  // 262144 packed output bits

__device__ __forceinline__ long long ddiv_floor(long long n, long long d) {
    double qd = (double)n / (double)d;
    long long q = (long long)qd;
    long long r = n - q * d;
    q -= (r < 0);
    q += (r >= d);
    return q;
}

// ---------- fast path: pow2 tf, 4..256 states, ns%32==0, payload fits LDS ----------
__device__ __forceinline__ void decode_fast(
    const unsigned* __restrict__ words, unsigned* tab, unsigned* obits,
    unsigned total_freq, int tf_shift, int num_symbols, int smask, unsigned pf0)
{
    const unsigned H = 0x80000000u;
    unsigned low = 0u, high = 0xFFFFFFFFu;
    unsigned dlt = words[0];                      // code - low
    unsigned long long bitbuf = (((unsigned long long)words[1]) << 32)
                              | (unsigned long long)words[2];
    int unavail = 64;
    unsigned pre = words[3];
    int widx = 4;
    unsigned wnext = words[4];

    const unsigned tfm2_2 = (total_freq - 2u) << 1;   // 8188 for tf=4096
    const double tfm2d = (double)(total_freq - 2u);
    const int tfm1 = (int)(total_freq - 1u);

    int st = 0;
    unsigned eN0 = 1u, ePK = 1u | (pf0 << 20);        // entry of st (current)
    int u1pS = -1; unsigned u1pN0 = 0u, u1pPK = 0u;   // prev iter's deferred write

    // reads for iteration 0 (children pair + 4 grandchildren of st)
    int cb = (st << 1) & smask;
    int gb = (st << 2) & smask;
    uint4 C  = *reinterpret_cast<const uint4*>(tab + 2 * cb);
    uint4 Ga = *reinterpret_cast<const uint4*>(tab + 2 * gb);
    uint4 Gb = *reinterpret_cast<const uint4*>(tab + 2 * gb + 4);

    const int iters = num_symbols >> 1;
    unsigned obuf = 0u;
    for (int it = 0; it < iters; ++it) {
        // ================= symbol 1 =================
        const unsigned pf1 = ePK >> 20;
        const unsigned n1a = ePK & 0xFFFFFu;
        const unsigned n0a = eN0;
        const unsigned rngm1 = high - low;
        const unsigned long long P1 = (unsigned long long)pf1 * rngm1 + pf1;
        const unsigned soff1 = (unsigned)(P1 >> tf_shift);
        const bool bt1 = (dlt >= soff1);
        const unsigned b1 = bt1 ? 1u : 0u;
        const unsigned split1 = low + soff1;
        unsigned lo = bt1 ? split1 : low;
        unsigned hi = bt1 ? high   : (split1 - 1u);
        unsigned dl = bt1 ? (dlt - soff1) : dlt;

        // speculative dual update for symbol 1 (shared rcp)
        const unsigned tt1 = n0a + n1a + 1u;
        const unsigned d21 = tt1 << 1;
        const float rcp1 = __builtin_amdgcn_rcpf((float)d21);
        const unsigned nA0 = n0a + 1u;                 // b=0 count0
        const unsigned numA = __umul24(tfm2_2, nA0) + tt1;
        const unsigned numB = numA - tfm2_2;           // b=1 numerator
        unsigned qA = (unsigned)((float)numA * rcp1);
        unsigned qB = (unsigned)((float)numB * rcp1);
        int rA = (int)(numA - __umul24(qA, d21));
        if (rA < 0)         { qA -= 1u; rA += (int)d21; }
        if (rA >= (int)d21) { qA += 1u; rA -= (int)d21; }
        int rB = (int)(numB - __umul24(qB, d21));
        if (rB < 0)         { qB -= 1u; rB += (int)d21; }
        if (rB >= (int)d21) { qB += 1u; rB -= (int)d21; }
        const unsigned nn0_1 = bt1 ? n0a : nA0;
        const unsigned nn1_1 = bt1 ? (n1a + 1u) : n1a;
        unsigned pfn1 = (bt1 ? qB : qA) + 1u;
        const int r1 = bt1 ? rB : rA;
        if (__builtin_expect(r1 == 0, 0)) {            // exact .5 tie (rare)
            asm volatile("");
            double p0d = (double)(int)nn0_1 / (double)(int)tt1;
            double pfd = rint(p0d * tfm2d) + 1.0;
            int pfi = (int)pfd;
            pfi = pfi < 1 ? 1 : (pfi > tfm1 ? tfm1 : pfi);
            pfn1 = (unsigned)pfi;
        }
        const unsigned npk1 = nn1_1 | (pfn1 << 20);

        // renorm 1
        {
            const unsigned x = lo ^ hi;
            const int k = __builtin_clz(x);
            const unsigned aa = ~(lo << (k + 1));
            const unsigned bv = (hi << (k + 1)) | ((2u << k) - 1u);
            const int m = __builtin_clz(aa | bv);
            const int K = k + m;
            const unsigned sub = (m != 0) ? H : 0u;
            const unsigned ones = (1u << K) - 1u;
            const unsigned tK = ((unsigned)(bitbuf >> 50)) >> (14 - K);
            lo = (lo << K) - sub;
            hi = (hi << K) + ones - sub;
            dl = (dl << K) | tK;
            bitbuf <<= K;
            unavail -= K;
        }

        // ================= symbol 2 =================
        const int s1 = cb | (int)b1;
        unsigned e2N0 = bt1 ? C.z : C.x;
        unsigned e2PK = bt1 ? C.w : C.y;
        if (__builtin_expect(s1 == u1pS, 0)) {         // missed deferred write
            asm volatile("");
            e2N0 = u1pN0; e2PK = u1pPK;
        }
        {   // self-loop: st's own (newer) update wins — unconditional cndmask
            const bool sl = (s1 == st);
            e2N0 = sl ? nn0_1 : e2N0;
            e2PK = sl ? npk1  : e2PK;
        }
        const unsigned pf2 = e2PK >> 20;
        const unsigned n1b = e2PK & 0xFFFFFu;
        const unsigned n0b = e2N0;
        const unsigned rngm2 = hi - lo;
        const unsigned long long P2 = (unsigned long long)pf2 * rngm2 + pf2;
        const unsigned soff2 = (unsigned)(P2 >> tf_shift);
        const bool bt2 = (dl >= soff2);
        const unsigned b2 = bt2 ? 1u : 0u;
        const unsigned split2 = lo + soff2;
        unsigned lo2 = bt2 ? split2 : lo;
        unsigned hi2 = bt2 ? hi     : (split2 - 1u);
        unsigned dl2 = bt2 ? (dl - soff2) : dl;

        // speculative dual update for symbol 2
        const unsigned tt2 = n0b + n1b + 1u;
        const unsigned d22 = tt2 << 1;
        const float rcp2 = __builtin_amdgcn_rcpf((float)d22);
        const unsigned nC0 = n0b + 1u;
        const unsigned numC = __umul24(tfm2_2, nC0) + tt2;
        const unsigned numD = numC - tfm2_2;
        unsigned qC = (unsigned)((float)numC * rcp2);
        unsigned qD = (unsigned)((float)numD * rcp2);
        int rC = (int)(numC - __umul24(qC, d22));
        if (rC < 0)         { qC -= 1u; rC += (int)d22; }
        if (rC >= (int)d22) { qC += 1u; rC -= (int)d22; }
        int rD = (int)(numD - __umul24(qD, d22));
        if (rD < 0)         { qD -= 1u; rD += (int)d22; }
        if (rD >= (int)d22) { qD += 1u; rD -= (int)d22; }
        const unsigned nn0_2 = bt2 ? n0b : nC0;
        const unsigned nn1_2 = bt2 ? (n1b + 1u) : n1b;
        unsigned pfn2 = (bt2 ? qD : qC) + 1u;
        const int r2 = bt2 ? rD : rC;
        if (__builtin_expect(r2 == 0, 0)) {
            asm volatile("");
            double p0d = (double)(int)nn0_2 / (double)(int)tt2;
            double pfd = rint(p0d * tfm2d) + 1.0;
            int pfi = (int)pfd;
            pfi = pfi < 1 ? 1 : (pfi > tfm1 ? tfm1 : pfi);
            pfn2 = (unsigned)pfi;
        }
        const unsigned npk2 = nn1_2 | (pfn2 << 20);

        // renorm 2
        int K2;
        {
            const unsigned x = lo2 ^ hi2;
            const int k = __builtin_clz(x);
            const unsigned aa = ~(lo2 << (k + 1));
            const unsigned bv = (hi2 << (k + 1)) | ((2u << k) - 1u);
            const int m = __builtin_clz(aa | bv);
            K2 = k + m;
            const unsigned sub = (m != 0) ? H : 0u;
            const unsigned ones = (1u << K2) - 1u;
            const unsigned tK = ((unsigned)(bitbuf >> 50)) >> (14 - K2);
            lo2 = (lo2 << K2) - sub;
            hi2 = (hi2 << K2) + ones - sub;
            dl2 = (dl2 << K2) | tK;
            bitbuf <<= K2;
            unavail -= K2;
        }

        // ============ next state + entry (selects + patches) ============
        const int s2 = ((s1 << 1) | (int)b2) & smask;
        // G holds entries gb..gb+3; index (b1<<1)|b2 == s2's slot
        const unsigned t0N = bt2 ? Ga.z : Ga.x;   // b1=0 row
        const unsigned t0P = bt2 ? Ga.w : Ga.y;
        const unsigned t1N = bt2 ? Gb.z : Gb.x;   // b1=1 row
        const unsigned t1P = bt2 ? Gb.w : Gb.y;
        unsigned eN = bt1 ? t1N : t0N;
        unsigned eP = bt1 ? t1P : t0P;
        if (__builtin_expect(s2 == u1pS, 0)) {        // oldest missed write
            asm volatile("");
            eN = u1pN0; eP = u1pPK;
        }
        {   // st's write (newer) — unconditional cndmask (npk1 long ready)
            const bool c = (s2 == st);
            eN = c ? nn0_1 : eN;
            eP = c ? npk1  : eP;
        }
        if (__builtin_expect(s2 == s1, 0)) {          // newest write (cold)
            asm volatile("");
            eN = nn0_2; eP = npk2;
        }

        // ============ writes, next reads (ORDER: wr(st), reads, wr(s1)) ====
        *reinterpret_cast<uint2*>(tab + 2 * st) = make_uint2(nn0_1, npk1);
        const int cbN = (s2 << 1) & smask;
        const int gbN = (s2 << 2) & smask;
        const uint4 Cn  = *reinterpret_cast<const uint4*>(tab + 2 * cbN);
        const uint4 GaN = *reinterpret_cast<const uint4*>(tab + 2 * gbN);
        const uint4 GbN = *reinterpret_cast<const uint4*>(tab + 2 * gbN + 4);
        *reinterpret_cast<uint2*>(tab + 2 * s1) = make_uint2(nn0_2, npk2);

        // carry state
        u1pS = s1; u1pN0 = nn0_2; u1pPK = npk2;
        st = s2; eN0 = eN; ePK = eP;
        cb = cbN; gb = gbN; C = Cn; Ga = GaN; Gb = GbN;
        low = lo2; high = hi2; dlt = dl2;

        // output bits + branchless refill (consumption <= 28, invariant >= 29)
        obuf = (obuf << 2) | (b1 << 1) | b2;
        const bool need = (unavail <= 32);
        const unsigned long long ins =
            (((unsigned long long)pre) << 32) >> (unavail & 63);
        bitbuf |= need ? ins : 0ull;
        unavail += need ? 32 : 0;
        pre = need ? wnext : pre;
        widx += need ? 1 : 0;
        const int wc = widx < (WORDS_LDS - 1) ? widx : (WORDS_LDS - 1);
        wnext = words[wc];

        if ((it & 15) == 15) obits[it >> 4] = obuf;   // 32 symbols per word
    }
}

// ---------- slow generic path (r5/r7/r8 hardware-verified LDS-table version) ----------
__device__ void decode_serial_slow(
    const unsigned* __restrict__ words, unsigned* tab, unsigned* obits,
    const int* __restrict__ bits, int nb, int nwords,
    unsigned total_freq, int num_symbols, int smask,
    unsigned pf0, float* __restrict__ out)
{
    const unsigned H = 0x80000000u;
    unsigned low = 0u, high = 0xFFFFFFFFu;
    unsigned code = words[0];
    unsigned long long bitbuf = (((unsigned long long)words[1]) << 32) | (unsigned long long)words[2];
    int navail = 64;
    unsigned pre = words[3];
    int widx = 4;

    const double tfm2d = (double)(total_freq - 2u);
    const int tfm1 = (int)(total_freq - 1u);

    int state = 0;
    unsigned n0 = 1u, n1 = 1u, pf = pf0;
    int wIdx = 0;
    unsigned wN0 = 1u, wN1 = 1u, wPf = pf0;
    unsigned obuf = 0u;

    for (int s = 0; s < num_symbols; ++s) {
        const int c0 = (state << 1) & smask;
        uint4 q = *reinterpret_cast<const uint4*>(tab + 2 * c0);
        if (navail <= 32) {
            bitbuf |= ((unsigned long long)pre) << (32 - navail);
            navail += 32;
            unsigned nxt = 0u;
            if (widx < WORDS_LDS) nxt = words[widx];
            else if (widx < nwords) {
                unsigned g = 0u;
                long long base = ((long long)widx) << 5;
                for (int j = 0; j < 32; ++j) {
                    long long idx = base + j;
                    int b = (idx < (long long)nb) ? (bits[idx] & 1) : 0;
                    g |= ((unsigned)b) << (31 - j);
                }
                nxt = g;
            }
            pre = nxt;
            ++widx;
        }
        const unsigned rngm1 = high - low;
        const unsigned long long P = (unsigned long long)pf * rngm1 + pf;
        const unsigned soff = (unsigned)ddiv_floor((long long)P, (long long)total_freq);
        const unsigned dlt = code - low;
        const int bit = (dlt >= soff) ? 1 : 0;
        const unsigned split = low + soff;
        low  = bit ? split : low;
        high = bit ? high : (split - 1u);
        obuf = (obuf << 1) | (unsigned)bit;

        const unsigned nn0 = n0 + (unsigned)(1 - bit);
        const unsigned nn1 = n1 + (unsigned)bit;
        double p0d = (double)(int)nn0 / (double)(int)(nn0 + nn1);
        double pfd = rint(p0d * tfm2d) + 1.0;
        int pfi = (int)pfd;
        pfi = pfi < 1 ? 1 : (pfi > tfm1 ? tfm1 : pfi);
        unsigned pfn = (unsigned)pfi;

        const unsigned x = low ^ high;
        const int k = __builtin_clz(x);
        const unsigned aa = ~(low << (k + 1));
        const unsigned bbv = (high << (k + 1)) | ((2u << k) - 1u);
        const int m = __builtin_clz(aa | bbv);
        const int K = k + m;
        const unsigned sub = (m != 0) ? H : 0u;
        const unsigned ones = (1u << K) - 1u;
        const unsigned tE = (unsigned)(bitbuf >> 34);   // EXT=30
        const unsigned tK = tE >> (30 - K);
        low  = (low << K) - sub;
        high = (high << K) + ones - sub;
        code = ((code << K) | tK) - sub;
        bitbuf <<= K;
        navail -= K;

        const int nidx = c0 | bit;
        const unsigned sw0 = bit ? q.z : q.x;
        const unsigned sw1 = bit ? q.w : q.y;
        const bool f2 = (nidx == wIdx);
        unsigned xn0 = f2 ? wN0 : sw0;
        unsigned xn1 = f2 ? wN1 : (sw1 & 0xFFFFFu);
        unsigned xpf = f2 ? wPf : (sw1 >> 20);
        *reinterpret_cast<uint2*>(tab + 2 * wIdx) = make_uint2(wN0, wN1 | (wPf << 20));
        wIdx = state; wN0 = nn0; wN1 = nn1; wPf = pfn;
        if (__builtin_expect(nidx == state, 0)) {
            asm volatile("");
            xn0 = nn0; xn1 = nn1; xpf = pfn;
        }
        state = nidx;
        n0 = xn0; n1 = xn1; pf = xpf;

        if ((s & 31) == 31) {
            int wo = s >> 5;
            if (wo < OBITS_WORDS) obits[wo] = obuf;
            else {
                int base = s & ~31;
                for (int j = 0; j < 32; ++j)
                    out[base + j] = ((obuf >> (31 - j)) & 1u) ? 1.0f : -1.0f;
            }
        }
    }
    if (num_symbols & 31) {
        int rem = num_symbols & 31;
        unsigned v = obuf << (32 - rem);
        int wo = num_symbols >> 5;
        if (wo < OBITS_WORDS) obits[wo] = v;
        else {
            int base = num_symbols & ~31;
            for (int j = 0; j < rem; ++j)
                out[base + j] = ((v >> (31 - j)) & 1u) ? 1.0f : -1.0f;
        }
    }
}

__global__ __launch_bounds__(256)
void EntropyDecoder_84928683311460_kernel(
    const int* __restrict__ bits,
    const int* __restrict__ tf_p,
    const int* __restrict__ ns_p,
    const int* __restrict__ cb_p,
    float* __restrict__ out,
    int nb)
{
    __shared__ unsigned words[WORDS_LDS];
    __shared__ __align__(16) unsigned tab[MAX_STATES * 2];  // {n0, n1|pf<<20}
    __shared__ unsigned obits[OBITS_WORDS];

    const int tid = threadIdx.x;
    const unsigned total_freq = (unsigned)(*tf_p);
    const int num_symbols = *ns_p;
    const int context_bits = *cb_p;
    const int num_states = 1 << context_bits;
    const int smask = num_states - 1;
    const int nwords = (nb + 31) >> 5;

    // ---- parallel: pack payload bits MSB-first into LDS; zero-pad tail ----
    for (int w = tid; w < WORDS_LDS; w += blockDim.x) {
        unsigned v = 0;
        int base = w << 5;
        if (base + 32 <= nb) {
            #pragma unroll
            for (int j = 0; j < 32; j += 4) {
                int4 b4 = *reinterpret_cast<const int4*>(bits + base + j);
                v |= ((unsigned)(b4.x & 1) << (31 - j))
                   | ((unsigned)(b4.y & 1) << (30 - j))
                   | ((unsigned)(b4.z & 1) << (29 - j))
                   | ((unsigned)(b4.w & 1) << (28 - j));
            }
        } else if (base < nb) {
            for (int j = 0; j < 32; ++j) {
                int idx = base + j;
                int b = (idx < nb) ? (bits[idx] & 1) : 0;
                v |= ((unsigned)b) << (31 - j);
            }
        }
        words[w] = v;
    }
    // init p0_freq for counts (1,1)
    unsigned pf0;
    {
        double pfd = rint(0.5 * (double)(total_freq - 2u)) + 1.0;
        int t = (int)pfd;
        int tfm1 = (int)(total_freq - 1u);
        t = t < 1 ? 1 : (t > tfm1 ? tfm1 : t);
        pf0 = (unsigned)t;
    }
    for (int st = tid; st < num_states; st += blockDim.x) {
        tab[2 * st]     = 1u;
        tab[2 * st + 1] = 1u | (pf0 << 20);
    }
    __syncthreads();

    const int tf_shift = 31 - __builtin_clz(total_freq);
    const bool pow2 = (total_freq & (total_freq - 1u)) == 0u;
    const unsigned long long bound =
        2ull * (unsigned long long)(total_freq - 2u) * (unsigned long long)(num_symbols + 1)
        + (unsigned long long)(num_symbols + 2);
    const bool fast = pow2 && total_freq >= 8u && total_freq <= 4096u
                      && bound < (1ull << 31)
                      && num_states >= 4 && num_states <= 256
                      && (num_symbols & 31) == 0 && num_symbols > 0
                      && num_symbols <= OBITS_WORDS * 32
                      && nwords <= 16384;

    if (tid == 0) {
        if (fast) {
            decode_fast(words, tab, obits, total_freq, tf_shift,
                        num_symbols, smask, pf0);
        } else {
            decode_serial_slow(words, tab, obits, bits, nb, nwords, total_freq,
                               num_symbols, smask, pf0, out);
        }
    }
    __syncthreads();

    // ---- parallel epilogue: expand packed bits -> {-1,+1} floats ----
    const int nwout = (num_symbols + 31) >> 5;
    const int npk = nwout < OBITS_WORDS ? nwout : OBITS_WORDS;
    for (int w = tid; w < npk; w += blockDim.x) {
        unsigned v = obits[w];
        int base = w << 5;
        if (base + 32 <= num_symbols) {
            #pragma unroll
            for (int j = 0; j < 32; j += 4) {
                float4 o;
                o.x = ((v >> (31 - j)) & 1u) ? 1.0f : -1.0f;
                o.y = ((v >> (30 - j)) & 1u) ? 1.0f : -1.0f;
                o.z = ((v >> (29 - j)) & 1u) ? 1.0f : -1.0f;
                o.w = ((v >> (28 - j)) & 1u) ? 1.0f : -1.0f;
                *reinterpret_cast<float4*>(out + base + j) = o;
            }
        } else {
            for (int j = 0; j < 32 && base + j < num_symbols; ++j)
                out[base + j] = ((v >> (31 - j)) & 1u) ? 1.0f : -1.0f;
        }
    }
}

extern "C" void kernel_launch(void* const* d_in, const int* in_sizes, int n_in,
                              void* d_out, int out_size, void* d_ws, size_t ws_size,
                              hipStream_t stream) {
    const int* bits = (const int*)d_in[0];
    const int* tf   = (const int*)d_in[1];
    const int* ns   = (const int*)d_in[2];
    const int* cb   = (const int*)d_in[3];
    float* out = (float*)d_out;
    int nb = in_sizes[0];

    hipLaunchKernelGGL(EntropyDecoder_84928683311460_kernel,
                       dim3(1), dim3(256), 0, stream,
                       bits, tf, ns, cb, out, nb);
}